// Round 5
// baseline (236.456 us; speedup 1.0000x reference)
//
#include <hip/hip_runtime.h>
#include <hip/hip_cooperative_groups.h>

namespace cg = cooperative_groups;

// BiaffineModule: B=4,S=256,H=768,F=32,T=256,WD=64,C=16
// out[b,s,e,c] = sum_u (sum_t s[b,s,t]U[t,c,u]) e[b,e,u]
//              + (s@Ws)[b,s,c] + (e@We)[b,e,c] + (wh@Ww+lin_b)[s,e,c]

#define B_ 4
#define S_ 256
#define H_ 768
#define F_ 32
#define T_ 256
#define C_ 16
#define R_ 1024
#define HF 800
#define HFP 832

typedef unsigned short u16;
typedef __attribute__((ext_vector_type(8))) short short8;
typedef __attribute__((ext_vector_type(4))) float f32x4;

__device__ __forceinline__ u16 f2b(float x) {
    unsigned u = __builtin_bit_cast(unsigned, x);
    u += 0x7FFF + ((u >> 16) & 1);          // RNE
    return (u16)(u >> 16);
}
__device__ __forceinline__ float b2f(u16 b) {
    unsigned u = ((unsigned)b) << 16;
    return __builtin_bit_cast(float, u);
}

// ---------------------------------------------------------------------------
// Direct-load NT GEMM core: A[M][K],Bt[N][K] fragments contiguous along K.
// ---------------------------------------------------------------------------
template<int K, int LDA, int LDB, int MF, int NF, int UNROLL>
__device__ __forceinline__ void core(const u16* __restrict__ A,
                                     const u16* __restrict__ B,
                                     int lr, int kgl, f32x4 acc[MF][NF])
{
    const u16* ap[MF];
    const u16* bp[NF];
#pragma unroll
    for (int i = 0; i < MF; ++i) ap[i] = A + (size_t)(i * 16 + lr) * LDA + kgl * 8;
#pragma unroll
    for (int j = 0; j < NF; ++j) bp[j] = B + (size_t)(j * 16 + lr) * LDB + kgl * 8;

#pragma unroll UNROLL
    for (int k = 0; k < K; k += 32) {
        short8 a[MF], b[NF];
#pragma unroll
        for (int i = 0; i < MF; ++i) a[i] = *(const short8*)(ap[i] + k);
#pragma unroll
        for (int j = 0; j < NF; ++j) b[j] = *(const short8*)(bp[j] + k);
#pragma unroll
        for (int i = 0; i < MF; ++i)
#pragma unroll
            for (int j = 0; j < NF; ++j)
                acc[i][j] = __builtin_amdgcn_mfma_f32_16x16x32_bf16(a[i], b[j], acc[i][j], 0, 0, 0);
    }
}

// ---------------------------------------------------------------------------
// Phase jobs (shared by cooperative mega-kernel and fallback dispatches)
// ---------------------------------------------------------------------------
__device__ __forceinline__ void prep_job(int bid, int tid,
    const float* __restrict__ fh, const float* __restrict__ fv,
    const float* __restrict__ sW, const float* __restrict__ eW,
    const float* __restrict__ U,  const float* __restrict__ WH,
    const float* __restrict__ linW, const float* __restrict__ linb,
    u16* __restrict__ Xb, u16* __restrict__ Wt, u16* __restrict__ Ut,
    float* __restrict__ WC, float* sh)
{
    if (bid < 832) {                               // --- cvtx + pad
        int idx = bid * 256 + tid;
        int r = idx / 208, c4 = idx % 208;
        int k = c4 * 4;
        float4 v;
        if (k < H_)       v = *(const float4*)&fh[r * H_ + k];
        else if (k < HF)  v = *(const float4*)&fv[r * F_ + k - H_];
        else              v = make_float4(0.f, 0.f, 0.f, 0.f);
        ushort4 o; o.x = f2b(v.x); o.y = f2b(v.y); o.z = f2b(v.z); o.w = f2b(v.w);
        *(ushort4*)&Xb[(size_t)r * HFP + k] = o;
    } else if (bid < 1232) {                       // --- cvtw (transpose)
        float (*t_)[33] = (float(*)[33])sh;
        int bid2 = bid - 832;
        int k0 = (bid2 / 16) * 32;
        int j0 = (bid2 % 16) * 32;
        const float* src = (j0 < T_) ? sW : eW;
        const int js = (j0 < T_) ? j0 : j0 - T_;
        {
            int jl = tid & 31, kl0 = (tid >> 5) * 4;
#pragma unroll
            for (int i = 0; i < 4; ++i)
                t_[kl0 + i][jl] = src[(k0 + kl0 + i) * T_ + js + jl];
        }
        __syncthreads();
        {
            int kl = tid & 31, jl0 = (tid >> 5) * 4;
#pragma unroll
            for (int i = 0; i < 4; ++i)
                Wt[(size_t)(j0 + jl0 + i) * HFP + k0 + kl] = f2b(t_[kl][jl0 + i]);
        }
        __syncthreads();
    } else if (bid < 1248) {                       // --- Wt pad
        int idx = (bid - 1232) * 256 + tid;
        int r = idx >> 3, c4 = idx & 7;
        ushort4 z; z.x = z.y = z.z = z.w = 0;
        *(ushort4*)&Wt[(size_t)r * HFP + HF + c4 * 4] = z;
    } else if (bid < 2272) {                       // --- cvtu (transpose)
        float (*t_)[33] = (float(*)[33])sh;
        int bid2 = bid - 1248;
        int cu0 = (bid2 >> 3) * 32;
        int t0  = (bid2 & 7) * 32;
        {
            int cul = tid & 31, tl0 = (tid >> 5) * 4;
#pragma unroll
            for (int i = 0; i < 4; ++i)
                t_[tl0 + i][cul] = U[(size_t)(t0 + tl0 + i) * 4096 + cu0 + cul];
        }
        __syncthreads();
        {
            int tl = tid & 31, cul0 = (tid >> 5) * 4;
#pragma unroll
            for (int i = 0; i < 4; ++i)
                Ut[(size_t)(cu0 + cul0 + i) * T_ + t0 + tl] = f2b(t_[tl][cul0 + i]);
        }
        __syncthreads();
    } else {                                       // --- wc
        float* Wl  = sh;          // [16][64]
        float* Wwl = sh + 1024;   // [64][16]
        int se0 = (bid - 2272) * 16;
        {
            int sel = tid >> 4, w4 = tid & 15;
            *(float4*)&Wl[sel * 64 + w4 * 4] = *(const float4*)&WH[(size_t)(se0 + sel) * 64 + w4 * 4];
        }
        {
            int w = tid >> 2, c4 = tid & 3;
            *(float4*)&Wwl[w * 16 + c4 * 4] = *(const float4*)&linW[(512 + w) * 16 + c4 * 4];
        }
        __syncthreads();
        int sel = tid >> 4, c = tid & 15;
        float acc = linb[c];
#pragma unroll
        for (int w = 0; w < 64; ++w)
            acc += Wl[sel * 64 + w] * Wwl[w * 16 + c];
        WC[(size_t)(se0 + sel) * 16 + c] = acc;
        __syncthreads();
    }
}

__device__ __forceinline__ void se_job(int job, int tid,
    const u16* __restrict__ Xb, const u16* __restrict__ Wt,
    const float* __restrict__ sb, const float* __restrict__ eb,
    u16* __restrict__ SEb)
{
    const int l = tid & 63, w = tid >> 6;
    const int wr = w >> 1, wc = w & 1;
    const int lr = l & 15, kgl = l >> 4;
    const int bm = (job & 7) * 64;    // j
    const int bn = (job >> 3) * 64;   // r
    f32x4 acc[2][2] = {};

    core<HFP, HFP, HFP, 2, 2, 2>(Wt + (size_t)(bm + wr * 32) * HFP,
                                 Xb + (size_t)(bn + wc * 32) * HFP,
                                 lr, kgl, acc);

#pragma unroll
    for (int i = 0; i < 2; ++i) {
        int j0 = bm + wr * 32 + i * 16 + kgl * 4;
        float4 bias = (j0 < T_) ? *(const float4*)&sb[j0]
                                : *(const float4*)&eb[j0 - T_];
#pragma unroll
        for (int jj = 0; jj < 2; ++jj) {
            int r = bn + wc * 32 + jj * 16 + lr;
            ushort4 o;
            o.x = f2b(acc[i][jj][0] + bias.x);
            o.y = f2b(acc[i][jj][1] + bias.y);
            o.z = f2b(acc[i][jj][2] + bias.z);
            o.w = f2b(acc[i][jj][3] + bias.w);
            *(ushort4*)&SEb[(size_t)r * 512 + j0] = o;
        }
    }
}

__device__ __forceinline__ void su_job(int bid, int tid,
    const u16* __restrict__ SEb, const u16* __restrict__ Ut,
    u16* __restrict__ SUb)
{
    const int l = tid & 63, w = tid >> 6;
    const int wr = w >> 1, wc = w & 1;
    const int lr = l & 15, kgl = l >> 4;
    const int bm = (bid & 31) * 128;   // cu
    const int bn = (bid >> 5) * 128;   // r
    f32x4 acc[4][4] = {};

    core<T_, T_, 512, 4, 4, 2>(Ut + (size_t)(bm + wr * 64) * T_,
                               SEb + (size_t)(bn + wc * 64) * 512,
                               lr, kgl, acc);

#pragma unroll
    for (int i = 0; i < 4; ++i) {
        int cu0 = bm + wr * 64 + i * 16 + kgl * 4;
#pragma unroll
        for (int j = 0; j < 4; ++j) {
            int r = bn + wc * 64 + j * 16 + lr;
            ushort4 o;
            o.x = f2b(acc[i][j][0]); o.y = f2b(acc[i][j][1]);
            o.z = f2b(acc[i][j][2]); o.w = f2b(acc[i][j][3]);
            *(ushort4*)&SUb[(size_t)r * 4096 + cu0] = o;
        }
    }
}

__device__ __forceinline__ void scec_job(int job, int tid,
    const u16* __restrict__ SEb, const float* __restrict__ linW,
    float* __restrict__ SCEC, float* sh)
{
    float* SEl = sh;                       // [4][512]
    const int r0 = job * 4;
#pragma unroll
    for (int i = 0; i < 2; ++i) {
        int ch = tid + i * 256;
        int rl = ch >> 7, o4 = (ch & 127) * 4;
        ushort4 v = *(const ushort4*)&SEb[(size_t)(r0 + rl) * 512 + o4];
        SEl[rl * 512 + o4 + 0] = b2f(v.x); SEl[rl * 512 + o4 + 1] = b2f(v.y);
        SEl[rl * 512 + o4 + 2] = b2f(v.z); SEl[rl * 512 + o4 + 3] = b2f(v.w);
    }
    __syncthreads();
    const int rl = tid >> 6, tq = (tid >> 4) & 3, c = tid & 15;
    const int t0 = tq * 64;
    float accs = 0.f, acce = 0.f;
#pragma unroll 4
    for (int t = t0; t < t0 + 64; ++t) {
        accs += SEl[rl * 512 + t]       * linW[t * 16 + c];
        acce += SEl[rl * 512 + 256 + t] * linW[(256 + t) * 16 + c];
    }
    accs += __shfl_xor(accs, 16); accs += __shfl_xor(accs, 32);
    acce += __shfl_xor(acce, 16); acce += __shfl_xor(acce, 32);
    if (tq == 0) {
        SCEC[(r0 + rl) * 32 + c]      = accs;
        SCEC[(r0 + rl) * 32 + 16 + c] = acce;
    }
    __syncthreads();
}

__device__ __forceinline__ void pre_job(int bid, int tid,
    const u16* __restrict__ SEb, const u16* __restrict__ SUb,
    const float* __restrict__ SCEC, const float* __restrict__ WC,
    float* __restrict__ OUT)
{
    const int b  = bid >> 7;
    const int q2 = bid & 127;
    const int bm = (q2 & 63) * 64;     // n = (s,c)
    const int bn = (q2 >> 6) * 128;    // e
    const int l = tid & 63, w = tid >> 6;
    const int wn = w >> 1, we = w & 1;
    const int lr = l & 15, kgl = l >> 4;
    f32x4 acc[2][4] = {};

    const u16* An = SUb + ((size_t)b << 20) + (size_t)(bm + wn * 32) * T_;
    const u16* Be = SEb + (size_t)(b << 8) * 512 + 256 + (size_t)(bn + we * 64) * 512;

    core<T_, T_, 512, 2, 4, 2>(An, Be, lr, kgl, acc);

    const int c0 = kgl * 4;
#pragma unroll
    for (int i = 0; i < 2; ++i) {
        int n0 = bm + wn * 32 + i * 16;      // 16-aligned
        int s = n0 >> 4;
        float4 scv = *(const float4*)&SCEC[((b << 8) + s) * 32 + c0];
#pragma unroll
        for (int j = 0; j < 4; ++j) {
            int e = bn + we * 64 + j * 16 + lr;
            float4 ecv = *(const float4*)&SCEC[((b << 8) + e) * 32 + 16 + c0];
            float4 wcv = *(const float4*)&WC[(size_t)(s * S_ + e) * 16 + c0];
            float4 o;
            o.x = acc[i][j][0] + scv.x + ecv.x + wcv.x;
            o.y = acc[i][j][1] + scv.y + ecv.y + wcv.y;
            o.z = acc[i][j][2] + scv.z + ecv.z + wcv.z;
            o.w = acc[i][j][3] + scv.w + ecv.w + wcv.w;
            *(float4*)&OUT[(((size_t)(b << 8) + s) * S_ + e) * 16 + c0] = o;
        }
    }
}

// ---------------------------------------------------------------------------
// Cooperative mega-kernel: 512 blocks, 4 phases separated by grid.sync()
// ---------------------------------------------------------------------------
__global__ __launch_bounds__(256, 2)
void k_all(const float* fh, const float* fv, const float* sW, const float* sb,
           const float* eW, const float* eb, const float* U, const float* WH,
           const float* linW, const float* linb,
           u16* Xb, u16* Wt, u16* Ut, float* WC, u16* SEb, float* SCEC,
           u16* SUb, float* OUT)
{
    __shared__ float sh[2112];
    cg::grid_group grid = cg::this_grid();
    const int nb  = gridDim.x;         // 512
    const int bid = blockIdx.x;
    const int tid = threadIdx.x;

    for (int job = bid; job < 6368; job += nb)
        prep_job(job, tid, fh, fv, sW, eW, U, WH, linW, linb, Xb, Wt, Ut, WC, sh);
    grid.sync();

    if (bid < 128)
        se_job(bid, tid, Xb, Wt, sb, eb, SEb);
    grid.sync();

    if (bid < 256) su_job(bid, tid, SEb, Ut, SUb);
    else           scec_job(bid - 256, tid, SEb, linW, SCEC, sh);
    grid.sync();

    pre_job(bid, tid, SEb, SUb, SCEC, WC, OUT);
}

// ---------------------------------------------------------------------------
// Fallback standalone kernels (same jobs, 4 dispatches)
// ---------------------------------------------------------------------------
__global__ __launch_bounds__(256)
void k_prep_sa(const float* fh, const float* fv, const float* sW, const float* eW,
               const float* U, const float* WH, const float* linW, const float* linb,
               u16* Xb, u16* Wt, u16* Ut, float* WC)
{
    __shared__ float sh[2112];
    prep_job(blockIdx.x, threadIdx.x, fh, fv, sW, eW, U, WH, linW, linb, Xb, Wt, Ut, WC, sh);
}
__global__ __launch_bounds__(256)
void k_se_sa(const u16* Xb, const u16* Wt, const float* sb, const float* eb, u16* SEb)
{
    se_job(blockIdx.x, threadIdx.x, Xb, Wt, sb, eb, SEb);
}
__global__ __launch_bounds__(256)
void k_suscec_sa(const u16* SEb, const u16* Ut, const float* linW, u16* SUb, float* SCEC)
{
    __shared__ float sh[2112];
    if (blockIdx.x < 256) su_job(blockIdx.x, threadIdx.x, SEb, Ut, SUb);
    else                  scec_job(blockIdx.x - 256, threadIdx.x, SEb, linW, SCEC, sh);
}
__global__ __launch_bounds__(256)
void k_pre_sa(const u16* SEb, const u16* SUb, const float* SCEC, const float* WC, float* OUT)
{
    pre_job(blockIdx.x, threadIdx.x, SEb, SUb, SCEC, WC, OUT);
}

// ---------------------------------------------------------------------------
extern "C" void kernel_launch(void* const* d_in, const int* in_sizes, int n_in,
                              void* d_out, int out_size, void* d_ws, size_t ws_size,
                              hipStream_t stream)
{
    const float* fh   = (const float*)d_in[0];
    const float* fv   = (const float*)d_in[1];
    const float* sW   = (const float*)d_in[2];
    const float* sb   = (const float*)d_in[3];
    const float* eW   = (const float*)d_in[4];
    const float* eb   = (const float*)d_in[5];
    const float* U    = (const float*)d_in[6];
    const float* WH   = (const float*)d_in[7];
    const float* linW = (const float*)d_in[8];
    const float* linb = (const float*)d_in[9];
    float* OUT = (float*)d_out;

    char* p = (char*)d_ws;
    u16* SUb = (u16*)p;      p += (size_t)B_ * 4096 * 256 * 2;
    float* WC = (float*)p;   p += (size_t)S_ * S_ * C_ * 4;
    u16* Ut  = (u16*)p;      p += (size_t)4096 * T_ * 2;
    u16* Xb  = (u16*)p;      p += (size_t)R_ * HFP * 2;
    u16* Wt  = (u16*)p;      p += (size_t)512 * HFP * 2;
    u16* SEb = (u16*)p;      p += (size_t)R_ * 512 * 2;
    float* SCEC = (float*)p; p += (size_t)R_ * 32 * 4;

    void* args[] = {(void*)&fh, (void*)&fv, (void*)&sW, (void*)&sb, (void*)&eW,
                    (void*)&eb, (void*)&U,  (void*)&WH, (void*)&linW, (void*)&linb,
                    (void*)&Xb, (void*)&Wt, (void*)&Ut, (void*)&WC, (void*)&SEb,
                    (void*)&SCEC, (void*)&SUb, (void*)&OUT};
    hipError_t err = hipLaunchCooperativeKernel((const void*)k_all, dim3(512), dim3(256),
                                                args, 0, stream);
    if (err != hipSuccess) {
        (void)hipGetLastError();     // clear sticky error, use fallback path
        k_prep_sa<<<dim3(6368), 256, 0, stream>>>(fh, fv, sW, eW, U, WH, linW, linb,
                                                  Xb, Wt, Ut, WC);
        k_se_sa<<<dim3(128), 256, 0, stream>>>(Xb, Wt, sb, eb, SEb);
        k_suscec_sa<<<dim3(512), 256, 0, stream>>>(SEb, Ut, linW, SUb, SCEC);
        k_pre_sa<<<dim3(512), 256, 0, stream>>>(SEb, SUb, SCEC, WC, OUT);
    }
}

// Round 6
// 64.268 us; speedup vs baseline: 3.6792x; 3.6792x over previous
//
#include <hip/hip_runtime.h>

// BiaffineModule: B=4,S=256,H=768,F=32,T=256,WD=64,C=16
// out[b,s,e,c] = sum_u (sum_t s[b,s,t]U[t,c,u]) e[b,e,u]
//              + (s@Ws)[b,s,c] + (e@We)[b,e,c] + (wh@Ww+lin_b)[s,e,c]

#define B_ 4
#define S_ 256
#define H_ 768
#define F_ 32
#define T_ 256
#define C_ 16
#define R_ 1024
#define HF 800
#define HFP 832

typedef unsigned short u16;
typedef __attribute__((ext_vector_type(8))) short short8;
typedef __attribute__((ext_vector_type(4))) float f32x4;

__device__ __forceinline__ u16 f2b(float x) {
    unsigned u = __builtin_bit_cast(unsigned, x);
    u += 0x7FFF + ((u >> 16) & 1);          // RNE
    return (u16)(u >> 16);
}
__device__ __forceinline__ float b2f(u16 b) {
    unsigned u = ((unsigned)b) << 16;
    return __builtin_bit_cast(float, u);
}

// ---------------------------------------------------------------------------
// Direct-load NT GEMM core: A[M][K],Bt[N][K] fragments contiguous along K.
// ---------------------------------------------------------------------------
template<int K, int LDA, int LDB, int MF, int NF, int UNROLL>
__device__ __forceinline__ void core(const u16* __restrict__ A,
                                     const u16* __restrict__ B,
                                     int lr, int kgl, f32x4 acc[MF][NF])
{
    const u16* ap[MF];
    const u16* bp[NF];
#pragma unroll
    for (int i = 0; i < MF; ++i) ap[i] = A + (size_t)(i * 16 + lr) * LDA + kgl * 8;
#pragma unroll
    for (int j = 0; j < NF; ++j) bp[j] = B + (size_t)(j * 16 + lr) * LDB + kgl * 8;

#pragma unroll UNROLL
    for (int k = 0; k < K; k += 32) {
        short8 a[MF], b[NF];
#pragma unroll
        for (int i = 0; i < MF; ++i) a[i] = *(const short8*)(ap[i] + k);
#pragma unroll
        for (int j = 0; j < NF; ++j) b[j] = *(const short8*)(bp[j] + k);
#pragma unroll
        for (int i = 0; i < MF; ++i)
#pragma unroll
            for (int j = 0; j < NF; ++j)
                acc[i][j] = __builtin_amdgcn_mfma_f32_16x16x32_bf16(a[i], b[j], acc[i][j], 0, 0, 0);
    }
}

// ---------------------------------------------------------------------------
// D1: conversions for SE inputs.  [0,832) cvtx | [832,1232) cvtw | [1232,1248) pad
// ---------------------------------------------------------------------------
__global__ __launch_bounds__(256)
void k_cvt1(const float* __restrict__ fh, const float* __restrict__ fv,
            const float* __restrict__ sW, const float* __restrict__ eW,
            u16* __restrict__ Xb, u16* __restrict__ Wt)
{
    const int bid = blockIdx.x;
    const int tid = threadIdx.x;

    if (bid < 832) {                               // --- cvtx + pad
        int idx = bid * 256 + tid;
        int r = idx / 208, c4 = idx % 208;
        int k = c4 * 4;
        float4 v;
        if (k < H_)       v = *(const float4*)&fh[r * H_ + k];
        else if (k < HF)  v = *(const float4*)&fv[r * F_ + k - H_];
        else              v = make_float4(0.f, 0.f, 0.f, 0.f);
        ushort4 o; o.x = f2b(v.x); o.y = f2b(v.y); o.z = f2b(v.z); o.w = f2b(v.w);
        *(ushort4*)&Xb[(size_t)r * HFP + k] = o;
    } else if (bid < 1232) {                       // --- cvtw (transpose)
        __shared__ float t_[32][33];
        int bid2 = bid - 832;
        int k0 = (bid2 / 16) * 32;
        int j0 = (bid2 % 16) * 32;
        const float* src = (j0 < T_) ? sW : eW;
        const int js = (j0 < T_) ? j0 : j0 - T_;
        {
            int jl = tid & 31, kl0 = (tid >> 5) * 4;
#pragma unroll
            for (int i = 0; i < 4; ++i)
                t_[kl0 + i][jl] = src[(k0 + kl0 + i) * T_ + js + jl];
        }
        __syncthreads();
        {
            int kl = tid & 31, jl0 = (tid >> 5) * 4;
#pragma unroll
            for (int i = 0; i < 4; ++i)
                Wt[(size_t)(j0 + jl0 + i) * HFP + k0 + kl] = f2b(t_[kl][jl0 + i]);
        }
    } else {                                       // --- Wt pad
        int idx = (bid - 1232) * 256 + tid;
        int r = idx >> 3, c4 = idx & 7;
        ushort4 z; z.x = z.y = z.z = z.w = 0;
        *(ushort4*)&Wt[(size_t)r * HFP + HF + c4 * 4] = z;
    }
}

// ---------------------------------------------------------------------------
// D2: SE GEMM (256 blocks, 32j x 64r) || cvtu (1024 blocks)
// ---------------------------------------------------------------------------
__global__ __launch_bounds__(256)
void k_se_cvtu(const u16* __restrict__ Xb, const u16* __restrict__ Wt,
               const float* __restrict__ sb, const float* __restrict__ eb,
               const float* __restrict__ U,
               u16* __restrict__ SEb, u16* __restrict__ Ut)
{
    const int bid = blockIdx.x;
    const int tid = threadIdx.x;

    if (bid < 256) {                               // --- SE
        const int l = tid & 63, w = tid >> 6;
        const int wj = w & 1, wr2 = w >> 1;
        const int lr = l & 15, kgl = l >> 4;
        const int bm = (bid & 15) * 32;            // j
        const int bn = (bid >> 4) * 64;            // r
        f32x4 acc[1][2] = {};

        core<HFP, HFP, HFP, 1, 2, 2>(Wt + (size_t)(bm + wj * 16) * HFP,
                                     Xb + (size_t)(bn + wr2 * 32) * HFP,
                                     lr, kgl, acc);

        int j0 = bm + wj * 16 + kgl * 4;
        float4 bias = (j0 < T_) ? *(const float4*)&sb[j0]
                                : *(const float4*)&eb[j0 - T_];
#pragma unroll
        for (int jj = 0; jj < 2; ++jj) {
            int r = bn + wr2 * 32 + jj * 16 + lr;
            ushort4 o;
            o.x = f2b(acc[0][jj][0] + bias.x);
            o.y = f2b(acc[0][jj][1] + bias.y);
            o.z = f2b(acc[0][jj][2] + bias.z);
            o.w = f2b(acc[0][jj][3] + bias.w);
            *(ushort4*)&SEb[(size_t)r * 512 + j0] = o;
        }
        return;
    }
    {                                              // --- cvtu (transpose)
        __shared__ float t_[32][33];
        int bid2 = bid - 256;
        int cu0 = (bid2 >> 3) * 32;
        int t0  = (bid2 & 7) * 32;
        {
            int cul = tid & 31, tl0 = (tid >> 5) * 4;
#pragma unroll
            for (int i = 0; i < 4; ++i)
                t_[tl0 + i][cul] = U[(size_t)(t0 + tl0 + i) * 4096 + cu0 + cul];
        }
        __syncthreads();
        {
            int tl = tid & 31, cul0 = (tid >> 5) * 4;
#pragma unroll
            for (int i = 0; i < 4; ++i)
                Ut[(size_t)(cu0 + cul0 + i) * T_ + t0 + tl] = f2b(t_[tl][cul0 + i]);
        }
    }
}

// ---------------------------------------------------------------------------
// D3: SU (512 blocks, 128cu x 64r) || SCEC (256) || WC (512 x 128 rows)
// ---------------------------------------------------------------------------
__global__ __launch_bounds__(256)
void k_su_scec_wc(const u16* __restrict__ SEb, const u16* __restrict__ Ut,
                  const float* __restrict__ linW, const float* __restrict__ linb,
                  const float* __restrict__ WH,
                  u16* __restrict__ SUb, float* __restrict__ SCEC,
                  float* __restrict__ WC)
{
    const int bid = blockIdx.x;
    const int tid = threadIdx.x;

    if (bid < 512) {                               // --- SU
        const int l = tid & 63, w = tid >> 6;
        const int wcu = w & 1, wr2 = w >> 1;
        const int lr = l & 15, kgl = l >> 4;
        const int bm = (bid & 31) * 128;           // cu
        const int bn = (bid >> 5) * 64;            // r
        f32x4 acc[4][2] = {};

        core<T_, T_, 512, 4, 2, 2>(Ut + (size_t)(bm + wcu * 64) * T_,
                                   SEb + (size_t)(bn + wr2 * 32) * 512,
                                   lr, kgl, acc);

#pragma unroll
        for (int i = 0; i < 4; ++i) {
            int cu0 = bm + wcu * 64 + i * 16 + kgl * 4;
#pragma unroll
            for (int j = 0; j < 2; ++j) {
                int r = bn + wr2 * 32 + j * 16 + lr;
                ushort4 o;
                o.x = f2b(acc[i][j][0]); o.y = f2b(acc[i][j][1]);
                o.z = f2b(acc[i][j][2]); o.w = f2b(acc[i][j][3]);
                *(ushort4*)&SUb[(size_t)r * 4096 + cu0] = o;
            }
        }
        return;
    }
    if (bid < 768) {                               // --- SCEC
        __shared__ float SEl[4][512];
        const int r0 = (bid - 512) * 4;
#pragma unroll
        for (int i = 0; i < 2; ++i) {
            int ch = tid + i * 256;
            int rl = ch >> 7, o4 = (ch & 127) * 4;
            ushort4 v = *(const ushort4*)&SEb[(size_t)(r0 + rl) * 512 + o4];
            SEl[rl][o4 + 0] = b2f(v.x); SEl[rl][o4 + 1] = b2f(v.y);
            SEl[rl][o4 + 2] = b2f(v.z); SEl[rl][o4 + 3] = b2f(v.w);
        }
        __syncthreads();
        const int rl = tid >> 6, tq = (tid >> 4) & 3, c = tid & 15;
        const int t0 = tq * 64;
        float accs = 0.f, acce = 0.f;
#pragma unroll 4
        for (int t = t0; t < t0 + 64; ++t) {
            accs += SEl[rl][t]       * linW[t * 16 + c];
            acce += SEl[rl][256 + t] * linW[(256 + t) * 16 + c];
        }
        accs += __shfl_xor(accs, 16); accs += __shfl_xor(accs, 32);
        acce += __shfl_xor(acce, 16); acce += __shfl_xor(acce, 32);
        if (tq == 0) {
            SCEC[(r0 + rl) * 32 + c]      = accs;
            SCEC[(r0 + rl) * 32 + 16 + c] = acce;
        }
        return;
    }
    {                                              // --- WC (128 rows/block)
        __shared__ float Wl[16][64];
        __shared__ float Wwl[64][16];
        const int se0 = (bid - 768) * 128;
        {
            int w0 = tid >> 2, c4 = tid & 3;
            *(float4*)&Wwl[w0][c4 * 4] = *(const float4*)&linW[(512 + w0) * 16 + c4 * 4];
        }
        const int sel = tid >> 4, c = tid & 15;
        const float lb = linb[c];
#pragma unroll
        for (int it = 0; it < 8; ++it) {
            __syncthreads();
            {
                int w4 = tid & 15;
                *(float4*)&Wl[sel][w4 * 4] =
                    *(const float4*)&WH[(size_t)(se0 + it * 16 + sel) * 64 + w4 * 4];
            }
            __syncthreads();
            float acc = lb;
#pragma unroll
            for (int w0 = 0; w0 < 64; ++w0)
                acc += Wl[sel][w0] * Wwl[w0][c];
            WC[(size_t)(se0 + it * 16 + sel) * 16 + c] = acc;
        }
    }
}

// ---------------------------------------------------------------------------
// D4: PRE (512 blocks): per b, M-op = SUb rows n=(s,c), N-op = SEb e-rows.
// ---------------------------------------------------------------------------
__global__ __launch_bounds__(256)
void k_pre(const u16* __restrict__ SEb, const u16* __restrict__ SUb,
           const float* __restrict__ SCEC, const float* __restrict__ WC,
           float* __restrict__ OUT)
{
    const int bid = blockIdx.x;
    const int tid = threadIdx.x;
    const int b  = bid >> 7;
    const int q2 = bid & 127;
    const int bm = (q2 & 63) * 64;     // n = (s,c)
    const int bn = (q2 >> 6) * 128;    // e
    const int l = tid & 63, w = tid >> 6;
    const int wn = w >> 1, we = w & 1;
    const int lr = l & 15, kgl = l >> 4;
    f32x4 acc[2][4] = {};

    const u16* An = SUb + ((size_t)b << 20) + (size_t)(bm + wn * 32) * T_;
    const u16* Be = SEb + (size_t)(b << 8) * 512 + 256 + (size_t)(bn + we * 64) * 512;

    core<T_, T_, 512, 2, 4, 2>(An, Be, lr, kgl, acc);

    const int c0 = kgl * 4;
#pragma unroll
    for (int i = 0; i < 2; ++i) {
        int n0 = bm + wn * 32 + i * 16;
        int s = n0 >> 4;
        float4 scv = *(const float4*)&SCEC[((b << 8) + s) * 32 + c0];
#pragma unroll
        for (int j = 0; j < 4; ++j) {
            int e = bn + we * 64 + j * 16 + lr;
            float4 ecv = *(const float4*)&SCEC[((b << 8) + e) * 32 + 16 + c0];
            float4 wcv = *(const float4*)&WC[(size_t)(s * S_ + e) * 16 + c0];
            float4 o;
            o.x = acc[i][j][0] + scv.x + ecv.x + wcv.x;
            o.y = acc[i][j][1] + scv.y + ecv.y + wcv.y;
            o.z = acc[i][j][2] + scv.z + ecv.z + wcv.z;
            o.w = acc[i][j][3] + scv.w + ecv.w + wcv.w;
            *(float4*)&OUT[(((size_t)(b << 8) + s) * S_ + e) * 16 + c0] = o;
        }
    }
}

// ---------------------------------------------------------------------------
extern "C" void kernel_launch(void* const* d_in, const int* in_sizes, int n_in,
                              void* d_out, int out_size, void* d_ws, size_t ws_size,
                              hipStream_t stream)
{
    const float* fh   = (const float*)d_in[0];
    const float* fv   = (const float*)d_in[1];
    const float* sW   = (const float*)d_in[2];
    const float* sb   = (const float*)d_in[3];
    const float* eW   = (const float*)d_in[4];
    const float* eb   = (const float*)d_in[5];
    const float* U    = (const float*)d_in[6];
    const float* WH   = (const float*)d_in[7];
    const float* linW = (const float*)d_in[8];
    const float* linb = (const float*)d_in[9];
    float* OUT = (float*)d_out;

    char* p = (char*)d_ws;
    u16* SUb = (u16*)p;      p += (size_t)B_ * 4096 * 256 * 2;
    float* WC = (float*)p;   p += (size_t)S_ * S_ * C_ * 4;
    u16* Ut  = (u16*)p;      p += (size_t)4096 * T_ * 2;
    u16* Xb  = (u16*)p;      p += (size_t)R_ * HFP * 2;
    u16* Wt  = (u16*)p;      p += (size_t)512 * HFP * 2;
    u16* SEb = (u16*)p;      p += (size_t)R_ * 512 * 2;
    float* SCEC = (float*)p; p += (size_t)R_ * 32 * 4;

    k_cvt1<<<dim3(1248), 256, 0, stream>>>(fh, fv, sW, eW, Xb, Wt);
    k_se_cvtu<<<dim3(1280), 256, 0, stream>>>(Xb, Wt, sb, eb, U, SEb, Ut);
    k_su_scec_wc<<<dim3(1280), 256, 0, stream>>>(SEb, Ut, linW, linb, WH,
                                                 SUb, SCEC, WC);
    k_pre<<<dim3(512), 256, 0, stream>>>(SEb, SUb, SCEC, WC, OUT);
}

// Round 7
// 62.013 us; speedup vs baseline: 3.8130x; 1.0364x over previous
//
#include <hip/hip_runtime.h>

// BiaffineModule: B=4,S=256,H=768,F=32,T=256,WD=64,C=16
// out[b,s,e,c] = sum_u (sum_t s[b,s,t]U[t,c,u]) e[b,e,u]
//              + (s@Ws)[b,s,c] + (e@We)[b,e,c] + (wh@Ww+lin_b)[s,e,c]

#define B_ 4
#define S_ 256
#define H_ 768
#define F_ 32
#define T_ 256
#define C_ 16
#define R_ 1024
#define HF 800

typedef unsigned short u16;
typedef __attribute__((ext_vector_type(8))) short short8;
typedef __attribute__((ext_vector_type(4))) float f32x4;

__device__ __forceinline__ u16 f2b(float x) {
    unsigned u = __builtin_bit_cast(unsigned, x);
    u += 0x7FFF + ((u >> 16) & 1);          // RNE
    return (u16)(u >> 16);
}
__device__ __forceinline__ float b2f(u16 b) {
    unsigned u = ((unsigned)b) << 16;
    return __builtin_bit_cast(float, u);
}
__device__ __forceinline__ short8 cvt8(float4 a, float4 b) {
    short8 r;
    r[0] = (short)f2b(a.x); r[1] = (short)f2b(a.y);
    r[2] = (short)f2b(a.z); r[3] = (short)f2b(a.w);
    r[4] = (short)f2b(b.x); r[5] = (short)f2b(b.y);
    r[6] = (short)f2b(b.z); r[7] = (short)f2b(b.w);
    return r;
}

// ---------------------------------------------------------------------------
// Direct-load NT GEMM core: A[M][K],Bt[N][K] fragments contiguous along K.
// ---------------------------------------------------------------------------
template<int K, int LDA, int LDB, int MF, int NF, int UNROLL>
__device__ __forceinline__ void core(const u16* __restrict__ A,
                                     const u16* __restrict__ B,
                                     int lr, int kgl, f32x4 acc[MF][NF])
{
    const u16* ap[MF];
    const u16* bp[NF];
#pragma unroll
    for (int i = 0; i < MF; ++i) ap[i] = A + (size_t)(i * 16 + lr) * LDA + kgl * 8;
#pragma unroll
    for (int j = 0; j < NF; ++j) bp[j] = B + (size_t)(j * 16 + lr) * LDB + kgl * 8;

#pragma unroll UNROLL
    for (int k = 0; k < K; k += 32) {
        short8 a[MF], b[NF];
#pragma unroll
        for (int i = 0; i < MF; ++i) a[i] = *(const short8*)(ap[i] + k);
#pragma unroll
        for (int j = 0; j < NF; ++j) b[j] = *(const short8*)(bp[j] + k);
#pragma unroll
        for (int i = 0; i < MF; ++i)
#pragma unroll
            for (int j = 0; j < NF; ++j)
                acc[i][j] = __builtin_amdgcn_mfma_f32_16x16x32_bf16(a[i], b[j], acc[i][j], 0, 0, 0);
    }
}

// ---------------------------------------------------------------------------
// D1: Wt bf16 [512][800] = [sW|eW]^T   (400 blocks)
// ---------------------------------------------------------------------------
__global__ __launch_bounds__(256)
void k_cvtw(const float* __restrict__ sW, const float* __restrict__ eW,
            u16* __restrict__ Wt)
{
    __shared__ float t_[32][33];
    const int bid = blockIdx.x;
    const int tid = threadIdx.x;
    int k0 = (bid / 16) * 32;              // 0..768
    int j0 = (bid % 16) * 32;
    const float* src = (j0 < T_) ? sW : eW;
    const int js = (j0 < T_) ? j0 : j0 - T_;
    {
        int jl = tid & 31, kl0 = (tid >> 5) * 4;
#pragma unroll
        for (int i = 0; i < 4; ++i)
            t_[kl0 + i][jl] = src[(k0 + kl0 + i) * T_ + js + jl];
    }
    __syncthreads();
    {
        int kl = tid & 31, jl0 = (tid >> 5) * 4;
#pragma unroll
        for (int i = 0; i < 4; ++i)
            Wt[(size_t)(j0 + jl0 + i) * HF + k0 + kl] = f2b(t_[kl][jl0 + i]);
    }
}

// ---------------------------------------------------------------------------
// D2: SE GEMM (128 blk, direct f32 x-loads) || cvtu (1024) || WC (512)
// SE bid map: bid = r_idx + 16*j_idx  (same-r blocks land on same XCD)
// ---------------------------------------------------------------------------
__global__ __launch_bounds__(256)
void k_se_cvtu_wc(const float* __restrict__ fh, const float* __restrict__ fv,
                  const u16* __restrict__ Wt,
                  const float* __restrict__ sb, const float* __restrict__ eb,
                  const float* __restrict__ U,
                  const float* __restrict__ linW, const float* __restrict__ linb,
                  const float* __restrict__ WH,
                  u16* __restrict__ SEb, u16* __restrict__ Ut,
                  float* __restrict__ WC)
{
    const int bid = blockIdx.x;
    const int tid = threadIdx.x;

    if (bid < 128) {                               // --- SE
        const int l = tid & 63, w = tid >> 6;
        const int wr = w >> 1, wc = w & 1;
        const int lr = l & 15, kgl = l >> 4;
        const int bm = (bid >> 4) * 64;            // j tile
        const int bn = (bid & 15) * 64;            // r tile
        f32x4 acc[2][2] = {};

        const u16* aw0 = Wt + (size_t)(bm + wr * 32 + lr) * HF + kgl * 8;
        const u16* aw1 = aw0 + (size_t)16 * HF;
        const float* xr0 = fh + (size_t)(bn + wc * 32 + lr) * H_ + kgl * 8;
        const float* xr1 = xr0 + (size_t)16 * H_;

#pragma unroll 4
        for (int k = 0; k < 768; k += 32) {
            short8 a0 = *(const short8*)(aw0 + k);
            short8 a1 = *(const short8*)(aw1 + k);
            float4 p0 = *(const float4*)(xr0 + k);
            float4 p1 = *(const float4*)(xr0 + k + 4);
            float4 q0 = *(const float4*)(xr1 + k);
            float4 q1 = *(const float4*)(xr1 + k + 4);
            short8 b0 = cvt8(p0, p1);
            short8 b1 = cvt8(q0, q1);
            acc[0][0] = __builtin_amdgcn_mfma_f32_16x16x32_bf16(a0, b0, acc[0][0], 0, 0, 0);
            acc[0][1] = __builtin_amdgcn_mfma_f32_16x16x32_bf16(a0, b1, acc[0][1], 0, 0, 0);
            acc[1][0] = __builtin_amdgcn_mfma_f32_16x16x32_bf16(a1, b0, acc[1][0], 0, 0, 0);
            acc[1][1] = __builtin_amdgcn_mfma_f32_16x16x32_bf16(a1, b1, acc[1][1], 0, 0, 0);
        }
        {   // tail: k = 768..799 from fv
            short8 a0 = *(const short8*)(aw0 + 768);
            short8 a1 = *(const short8*)(aw1 + 768);
            const float* v0 = fv + (size_t)(bn + wc * 32 + lr) * F_ + kgl * 8;
            const float* v1 = v0 + (size_t)16 * F_;
            short8 b0 = cvt8(*(const float4*)v0, *(const float4*)(v0 + 4));
            short8 b1 = cvt8(*(const float4*)v1, *(const float4*)(v1 + 4));
            acc[0][0] = __builtin_amdgcn_mfma_f32_16x16x32_bf16(a0, b0, acc[0][0], 0, 0, 0);
            acc[0][1] = __builtin_amdgcn_mfma_f32_16x16x32_bf16(a0, b1, acc[0][1], 0, 0, 0);
            acc[1][0] = __builtin_amdgcn_mfma_f32_16x16x32_bf16(a1, b0, acc[1][0], 0, 0, 0);
            acc[1][1] = __builtin_amdgcn_mfma_f32_16x16x32_bf16(a1, b1, acc[1][1], 0, 0, 0);
        }

#pragma unroll
        for (int i = 0; i < 2; ++i) {
            int j0 = bm + wr * 32 + i * 16 + kgl * 4;
            float4 bias = (j0 < T_) ? *(const float4*)&sb[j0]
                                    : *(const float4*)&eb[j0 - T_];
#pragma unroll
            for (int jj = 0; jj < 2; ++jj) {
                int r = bn + wc * 32 + jj * 16 + lr;
                ushort4 o;
                o.x = f2b(acc[i][jj][0] + bias.x);
                o.y = f2b(acc[i][jj][1] + bias.y);
                o.z = f2b(acc[i][jj][2] + bias.z);
                o.w = f2b(acc[i][jj][3] + bias.w);
                *(ushort4*)&SEb[(size_t)r * 512 + j0] = o;
            }
        }
        return;
    }
    if (bid < 1152) {                              // --- cvtu (transpose)
        __shared__ float t_[32][33];
        int bid2 = bid - 128;
        int cu0 = (bid2 >> 3) * 32;
        int t0  = (bid2 & 7) * 32;
        {
            int cul = tid & 31, tl0 = (tid >> 5) * 4;
#pragma unroll
            for (int i = 0; i < 4; ++i)
                t_[tl0 + i][cul] = U[(size_t)(t0 + tl0 + i) * 4096 + cu0 + cul];
        }
        __syncthreads();
        {
            int tl = tid & 31, cul0 = (tid >> 5) * 4;
#pragma unroll
            for (int i = 0; i < 4; ++i)
                Ut[(size_t)(cu0 + cul0 + i) * T_ + t0 + tl] = f2b(t_[tl][cul0 + i]);
        }
        return;
    }
    {                                              // --- WC (128 rows/block)
        __shared__ float Wl[16][64];
        __shared__ float Wwl[64][16];
        const int se0 = (bid - 1152) * 128;
        {
            int w0 = tid >> 2, c4 = tid & 3;
            *(float4*)&Wwl[w0][c4 * 4] = *(const float4*)&linW[(512 + w0) * 16 + c4 * 4];
        }
        const int sel = tid >> 4, c = tid & 15;
        const float lb = linb[c];
#pragma unroll
        for (int it = 0; it < 8; ++it) {
            __syncthreads();
            {
                int w4 = tid & 15;
                *(float4*)&Wl[sel][w4 * 4] =
                    *(const float4*)&WH[(size_t)(se0 + it * 16 + sel) * 64 + w4 * 4];
            }
            __syncthreads();
            float acc = lb;
#pragma unroll
            for (int w0 = 0; w0 < 64; ++w0)
                acc += Wl[sel][w0] * Wwl[w0][c];
            WC[(size_t)(se0 + it * 16 + sel) * 16 + c] = acc;
        }
    }
}

// ---------------------------------------------------------------------------
// D3: SU (256 blk, 128cu x 128r, waves 64x64 = 4x4 frags) || SCEC (256)
// SU bid map: bid = r_idx*32 + cu_idx (same-cu blocks share an XCD)
// ---------------------------------------------------------------------------
__global__ __launch_bounds__(256)
void k_su_scec(const u16* __restrict__ SEb, const u16* __restrict__ Ut,
               const float* __restrict__ linW,
               u16* __restrict__ SUb, float* __restrict__ SCEC)
{
    const int bid = blockIdx.x;
    const int tid = threadIdx.x;

    if (bid < 256) {                               // --- SU
        const int l = tid & 63, w = tid >> 6;
        const int wcu = w & 1, wr2 = w >> 1;
        const int lr = l & 15, kgl = l >> 4;
        const int bm = (bid & 31) * 128;           // cu
        const int bn = (bid >> 5) * 128;           // r
        f32x4 acc[4][4] = {};

        core<T_, T_, 512, 4, 4, 2>(Ut + (size_t)(bm + wcu * 64) * T_,
                                   SEb + (size_t)(bn + wr2 * 64) * 512,
                                   lr, kgl, acc);

#pragma unroll
        for (int i = 0; i < 4; ++i) {
            int cu0 = bm + wcu * 64 + i * 16 + kgl * 4;
#pragma unroll
            for (int j = 0; j < 4; ++j) {
                int r = bn + wr2 * 64 + j * 16 + lr;
                ushort4 o;
                o.x = f2b(acc[i][j][0]); o.y = f2b(acc[i][j][1]);
                o.z = f2b(acc[i][j][2]); o.w = f2b(acc[i][j][3]);
                *(ushort4*)&SUb[(size_t)r * 4096 + cu0] = o;
            }
        }
        return;
    }
    {                                              // --- SCEC
        __shared__ float SEl[4][512];
        const int r0 = (bid - 256) * 4;
#pragma unroll
        for (int i = 0; i < 2; ++i) {
            int ch = tid + i * 256;
            int rl = ch >> 7, o4 = (ch & 127) * 4;
            ushort4 v = *(const ushort4*)&SEb[(size_t)(r0 + rl) * 512 + o4];
            SEl[rl][o4 + 0] = b2f(v.x); SEl[rl][o4 + 1] = b2f(v.y);
            SEl[rl][o4 + 2] = b2f(v.z); SEl[rl][o4 + 3] = b2f(v.w);
        }
        __syncthreads();
        const int rl = tid >> 6, tq = (tid >> 4) & 3, c = tid & 15;
        const int t0 = tq * 64;
        float accs = 0.f, acce = 0.f;
#pragma unroll 4
        for (int t = t0; t < t0 + 64; ++t) {
            accs += SEl[rl][t]       * linW[t * 16 + c];
            acce += SEl[rl][256 + t] * linW[(256 + t) * 16 + c];
        }
        accs += __shfl_xor(accs, 16); accs += __shfl_xor(accs, 32);
        acce += __shfl_xor(acce, 16); acce += __shfl_xor(acce, 32);
        if (tq == 0) {
            SCEC[(r0 + rl) * 32 + c]      = accs;
            SCEC[(r0 + rl) * 32 + 16 + c] = acce;
        }
    }
}

// ---------------------------------------------------------------------------
// D4: PRE (512 blk): tile 64n x 128e per b; waves 32n x 64e = 2x4 frags.
// bid map: bid = n_idx*8 + b*2 + e_idx  (same (b,e) group shares an XCD)
// ---------------------------------------------------------------------------
__global__ __launch_bounds__(256)
void k_pre(const u16* __restrict__ SEb, const u16* __restrict__ SUb,
           const float* __restrict__ SCEC, const float* __restrict__ WC,
           float* __restrict__ OUT)
{
    const int bid = blockIdx.x;
    const int tid = threadIdx.x;
    const int n_idx = bid >> 3;
    const int b  = (bid >> 1) & 3;
    const int e_idx = bid & 1;
    const int bm = n_idx * 64;         // n = (s,c)
    const int bn = e_idx * 128;        // e
    const int l = tid & 63, w = tid >> 6;
    const int wn = w >> 1, we = w & 1;
    const int lr = l & 15, kgl = l >> 4;
    f32x4 acc[2][4] = {};

    const u16* An = SUb + ((size_t)b << 20) + (size_t)(bm + wn * 32) * T_;
    const u16* Be = SEb + (size_t)(b << 8) * 512 + 256 + (size_t)(bn + we * 64) * 512;

    core<T_, T_, 512, 2, 4, 4>(An, Be, lr, kgl, acc);

    const int c0 = kgl * 4;
#pragma unroll
    for (int i = 0; i < 2; ++i) {
        int n0 = bm + wn * 32 + i * 16;
        int s = n0 >> 4;
        float4 scv = *(const float4*)&SCEC[((b << 8) + s) * 32 + c0];
#pragma unroll
        for (int j = 0; j < 4; ++j) {
            int e = bn + we * 64 + j * 16 + lr;
            float4 ecv = *(const float4*)&SCEC[((b << 8) + e) * 32 + 16 + c0];
            float4 wcv = *(const float4*)&WC[(size_t)(s * S_ + e) * 16 + c0];
            float4 o;
            o.x = acc[i][j][0] + scv.x + ecv.x + wcv.x;
            o.y = acc[i][j][1] + scv.y + ecv.y + wcv.y;
            o.z = acc[i][j][2] + scv.z + ecv.z + wcv.z;
            o.w = acc[i][j][3] + scv.w + ecv.w + wcv.w;
            *(float4*)&OUT[(((size_t)(b << 8) + s) * S_ + e) * 16 + c0] = o;
        }
    }
}

// ---------------------------------------------------------------------------
extern "C" void kernel_launch(void* const* d_in, const int* in_sizes, int n_in,
                              void* d_out, int out_size, void* d_ws, size_t ws_size,
                              hipStream_t stream)
{
    const float* fh   = (const float*)d_in[0];
    const float* fv   = (const float*)d_in[1];
    const float* sW   = (const float*)d_in[2];
    const float* sb   = (const float*)d_in[3];
    const float* eW   = (const float*)d_in[4];
    const float* eb   = (const float*)d_in[5];
    const float* U    = (const float*)d_in[6];
    const float* WH   = (const float*)d_in[7];
    const float* linW = (const float*)d_in[8];
    const float* linb = (const float*)d_in[9];
    float* OUT = (float*)d_out;

    char* p = (char*)d_ws;
    u16* SUb = (u16*)p;      p += (size_t)B_ * 4096 * 256 * 2;   // 8 MB
    float* WC = (float*)p;   p += (size_t)S_ * S_ * C_ * 4;      // 4 MB
    u16* Ut  = (u16*)p;      p += (size_t)4096 * T_ * 2;         // 2 MB
    u16* Wt  = (u16*)p;      p += (size_t)512 * HF * 2;          // 0.8 MB
    u16* SEb = (u16*)p;      p += (size_t)R_ * 512 * 2;          // 1 MB
    float* SCEC = (float*)p; p += (size_t)R_ * 32 * 4;           // 128 KB

    k_cvtw<<<dim3(400), 256, 0, stream>>>(sW, eW, Wt);
    k_se_cvtu_wc<<<dim3(1664), 256, 0, stream>>>(fh, fv, Wt, sb, eb, U,
                                                 linW, linb, WH, SEb, Ut, WC);
    k_su_scec<<<dim3(512), 256, 0, stream>>>(SEb, Ut, linW, SUb, SCEC);
    k_pre<<<dim3(512), 256, 0, stream>>>(SEb, SUb, SCEC, WC, OUT);
}